// Round 1
// baseline (420.013 us; speedup 1.0000x reference)
//
#include <hip/hip_runtime.h>
#include <hip/hip_bf16.h>
#include <stdint.h>

using bf16_t = __hip_bfloat16;
typedef __bf16 bf16x8 __attribute__((ext_vector_type(8)));
typedef float f32x4 __attribute__((ext_vector_type(4)));

// ---------------------------------------------------------------- helpers
__device__ __forceinline__ void async_lds16(const void* g, void* l) {
  // global -> LDS direct copy, 16B per lane. LDS dest is wave-uniform base +
  // lane*16 (guide m104/m108); we pass the wave-uniform base pointer.
  __builtin_amdgcn_global_load_lds(
      (const __attribute__((address_space(1))) void*)g,
      (__attribute__((address_space(3))) void*)l, 16, 0, 0);
}

__device__ __forceinline__ unsigned short f2bf_u16(float f) {
  __hip_bfloat16 h = __float2bfloat16(f);
  return __builtin_bit_cast(unsigned short, h);
}

// ---------------------------------------------------------------- convert x
__global__ __launch_bounds__(256) void convert_x_kernel(
    const float* __restrict__ x, bf16_t* __restrict__ xb) {
  size_t i = ((size_t)blockIdx.x * 256 + threadIdx.x) * 4;
  float4 v = *(const float4*)(x + i);
  ushort4 o;
  o.x = f2bf_u16(v.x);
  o.y = f2bf_u16(v.y);
  o.z = f2bf_u16(v.z);
  o.w = f2bf_u16(v.w);
  *(ushort4*)(xb + i) = o;
}

// ------------------------------------------------ convert + transpose W (3x)
// W: [1024][1024] f32 row-major  ->  WT: [1024][1024] bf16, WT[n][k]=W[k][n]
__global__ __launch_bounds__(256) void convert_transpose_w_kernel(
    const float* __restrict__ Wq, const float* __restrict__ Wk,
    const float* __restrict__ Wv, bf16_t* __restrict__ wt) {
  __shared__ bf16_t tile[32][33];
  const float* W = (blockIdx.z == 0) ? Wq : (blockIdx.z == 1) ? Wk : Wv;
  bf16_t* WT = wt + (size_t)blockIdx.z * 1024 * 1024;
  const int tx = threadIdx.x & 31;
  const int ty = threadIdx.x >> 5;           // 0..7
  const int bx = blockIdx.x & 31;            // col tile
  const int by = blockIdx.x >> 5;            // row tile
  const int k0 = by * 32, n0 = bx * 32;
#pragma unroll
  for (int j = 0; j < 32; j += 8)
    tile[ty + j][tx] = __float2bfloat16(W[(size_t)(k0 + ty + j) * 1024 + n0 + tx]);
  __syncthreads();
#pragma unroll
  for (int j = 0; j < 32; j += 8)
    WT[(size_t)(n0 + ty + j) * 1024 + k0 + tx] = tile[tx][ty + j];
}

// ---------------------------------------------------------------- GEMM
// C[M,N] = A[M,K] * BT[N,K]^T   (both operands k-contiguous bf16)
// 128x128 tile, BK=32, 256 threads = 4 waves (2x2), 64x64 per wave,
// mfma_f32_16x16x32_bf16, global_load_lds width-16 staging (m97 structure).
// OUT_MODE: 0 = bf16 row-major, 1 = bf16 transposed batched (VT),
//           2 = f32 row-major.
template <int OUT_MODE, bool CAUSAL_SKIP, bool KLIMIT>
__global__ __launch_bounds__(256) void gemm_bt_kernel(
    const bf16_t* __restrict__ A, const bf16_t* __restrict__ BT,
    void* __restrict__ Cv, int M, int N, int K, int lda, int ldb, int ldc) {
  const int m0 = blockIdx.y * 128;
  const int n0 = blockIdx.x * 128;
  if (CAUSAL_SKIP && n0 > m0) return;  // tile entirely above causal diagonal
  int nkt = K >> 5;
  if (KLIMIT) {
    int lim = (m0 + 128) >> 5;  // causal: only k (= s) <= tile row max needed
    nkt = nkt < lim ? nkt : lim;
  }

  __shared__ bf16_t lsA[128 * 32];
  __shared__ bf16_t lsB[128 * 32];

  const int tid = threadIdx.x;
  const int wid = tid >> 6;
  const int lane = tid & 63;
  const int wr = wid >> 1;  // wave row 0..1
  const int wc = wid & 1;   // wave col 0..1

  f32x4 acc[4][4];
  const f32x4 zero = {0.f, 0.f, 0.f, 0.f};
#pragma unroll
  for (int m = 0; m < 4; ++m)
#pragma unroll
    for (int n = 0; n < 4; ++n) acc[m][n] = zero;

  // staging addressing: thread tid covers LDS bytes tid*16 (+4096 for 2nd half)
  const int srow = tid >> 2;       // 0..63 row within half tile
  const int scol = (tid & 3) * 8;  // k-col base
  const bf16_t* gA = A + (size_t)(m0 + srow) * lda + scol;
  const bf16_t* gB = BT + (size_t)(n0 + srow) * ldb + scol;
  const size_t gAstep64 = (size_t)64 * lda;
  const size_t gBstep64 = (size_t)64 * ldb;

  bf16_t* lA0 = lsA + wid * 512;
  bf16_t* lA1 = lsA + 2048 + wid * 512;
  bf16_t* lB0 = lsB + wid * 512;
  bf16_t* lB1 = lsB + 2048 + wid * 512;

  // fragment addressing (A: row=lane&15, k=(lane>>4)*8; B^T rows likewise)
  const int frow = lane & 15;
  const int fk = (lane >> 4) * 8;
  const int aoff = (wr * 64 + frow) * 32 + fk;
  const int boff = (wc * 64 + frow) * 32 + fk;

  for (int kt = 0; kt < nkt; ++kt) {
    __syncthreads();  // previous tile's ds_reads are done (lgkm drained)
    async_lds16(gA, lA0);
    async_lds16(gA + gAstep64, lA1);
    async_lds16(gB, lB0);
    async_lds16(gB + gBstep64, lB1);
    gA += 32;
    gB += 32;
    __syncthreads();  // compiler inserts vmcnt(0) drain before barrier

    bf16x8 af[4], bfr[4];
#pragma unroll
    for (int m = 0; m < 4; ++m)
      af[m] = *(const bf16x8*)(lsA + aoff + m * 16 * 32);
#pragma unroll
    for (int n = 0; n < 4; ++n)
      bfr[n] = *(const bf16x8*)(lsB + boff + n * 16 * 32);
#pragma unroll
    for (int m = 0; m < 4; ++m)
#pragma unroll
      for (int n = 0; n < 4; ++n)
        acc[m][n] =
            __builtin_amdgcn_mfma_f32_16x16x32_bf16(af[m], bfr[n], acc[m][n], 0, 0, 0);
  }

  // epilogue: C/D frag layout col=lane&15, row=(lane>>4)*4+j (m89/m91)
  const int erow = wr * 64 + (lane >> 4) * 4;
  const int ecol = wc * 64 + (lane & 15);
  if (OUT_MODE == 0) {
    bf16_t* C = (bf16_t*)Cv;
#pragma unroll
    for (int m = 0; m < 4; ++m)
#pragma unroll
      for (int n = 0; n < 4; ++n)
#pragma unroll
        for (int j = 0; j < 4; ++j) {
          int r = m0 + erow + m * 16 + j;
          int c = n0 + ecol + n * 16;
          C[(size_t)r * ldc + c] = __float2bfloat16(acc[m][n][j]);
        }
  } else if (OUT_MODE == 1) {
    // V^T batched: global row r in [0,8192) -> b=r>>11, t=r&2047
    // VT[b][d][t] at ((b*1024 + d)*2048 + t)
    bf16_t* C = (bf16_t*)Cv;
#pragma unroll
    for (int m = 0; m < 4; ++m)
#pragma unroll
      for (int n = 0; n < 4; ++n)
#pragma unroll
        for (int j = 0; j < 4; ++j) {
          int r = m0 + erow + m * 16 + j;
          int c = n0 + ecol + n * 16;
          int b = r >> 11, t = r & 2047;
          C[((size_t)b * 1024 + c) * 2048 + t] = __float2bfloat16(acc[m][n][j]);
        }
  } else {
    float* C = (float*)Cv;
#pragma unroll
    for (int m = 0; m < 4; ++m)
#pragma unroll
      for (int n = 0; n < 4; ++n)
#pragma unroll
        for (int j = 0; j < 4; ++j) {
          int r = m0 + erow + m * 16 + j;
          int c = n0 + ecol + n * 16;
          C[(size_t)r * ldc + c] = acc[m][n][j];
        }
  }
}

// ---------------------------------------------------------------- softmax
// One wave per row t: read S[t][0..2047] f32, causal-masked softmax of
// scale*S, write P[t][0..2047] bf16 IN PLACE at the row start (row is fully
// register-staged before any store). Upper triangle written as 0.
__global__ __launch_bounds__(256) void softmax_causal_kernel(float* __restrict__ S) {
  const int lane = threadIdx.x & 63;
  const int row = blockIdx.x * 4 + (threadIdx.x >> 6);
  float* srow = S + (size_t)row * 2048;

  float4 v[8];
#pragma unroll
  for (int it = 0; it < 8; ++it) v[it] = *(const float4*)(srow + (it * 64 + lane) * 4);

  float mx = -3.0e38f;
#pragma unroll
  for (int it = 0; it < 8; ++it) {
    int s0 = (it * 64 + lane) * 4;
    if (s0 + 0 <= row) mx = fmaxf(mx, v[it].x);
    if (s0 + 1 <= row) mx = fmaxf(mx, v[it].y);
    if (s0 + 2 <= row) mx = fmaxf(mx, v[it].z);
    if (s0 + 3 <= row) mx = fmaxf(mx, v[it].w);
  }
#pragma unroll
  for (int off = 32; off > 0; off >>= 1) mx = fmaxf(mx, __shfl_xor(mx, off, 64));

  const float kMul = 0.03125f * 1.4426950408889634f;  // scale * log2(e)
  float p[8][4];
  float sum = 0.f;
#pragma unroll
  for (int it = 0; it < 8; ++it) {
    int s0 = (it * 64 + lane) * 4;
    float e0 = (s0 + 0 <= row) ? exp2f((v[it].x - mx) * kMul) : 0.f;
    float e1 = (s0 + 1 <= row) ? exp2f((v[it].y - mx) * kMul) : 0.f;
    float e2 = (s0 + 2 <= row) ? exp2f((v[it].z - mx) * kMul) : 0.f;
    float e3 = (s0 + 3 <= row) ? exp2f((v[it].w - mx) * kMul) : 0.f;
    p[it][0] = e0; p[it][1] = e1; p[it][2] = e2; p[it][3] = e3;
    sum += (e0 + e1) + (e2 + e3);
  }
#pragma unroll
  for (int off = 32; off > 0; off >>= 1) sum += __shfl_xor(sum, off, 64);
  const float inv = 1.f / sum;

  bf16_t* prow = (bf16_t*)srow;  // in-place: bf16 row occupies first 4KB of row
#pragma unroll
  for (int it = 0; it < 8; ++it) {
    ushort4 o;
    o.x = f2bf_u16(p[it][0] * inv);
    o.y = f2bf_u16(p[it][1] * inv);
    o.z = f2bf_u16(p[it][2] * inv);
    o.w = f2bf_u16(p[it][3] * inv);
    *(ushort4*)(prow + (it * 64 + lane) * 4) = o;
  }
}

// ---------------------------------------------------------------- launch
extern "C" void kernel_launch(void* const* d_in, const int* in_sizes, int n_in,
                              void* d_out, int out_size, void* d_ws, size_t ws_size,
                              hipStream_t stream) {
  (void)in_sizes; (void)n_in; (void)out_size; (void)ws_size;
  const float* x = (const float*)d_in[0];
  const float* Wq = (const float*)d_in[1];
  const float* Wk = (const float*)d_in[2];
  const float* Wv = (const float*)d_in[3];
  float* out = (float*)d_out;

  // workspace layout (bytes):
  //   [0, 16.8M)       xb  (bf16 x, 8192x1024)  -- reused per-batch as S (f32 2048x2048)
  //   [16.8M, 23.1M)   wqt/wkt/wvt (bf16 1024x1024 each)
  //   [23.1M, 39.8M)   Q   (bf16 8192x1024)
  //   [39.8M, 56.6M)   K   (bf16 8192x1024)
  //   [56.6M, 73.4M)   VT  (bf16 [4][1024][2048])
  char* ws = (char*)d_ws;
  bf16_t* xb = (bf16_t*)ws;
  float* S = (float*)ws;
  bf16_t* wqt = (bf16_t*)(ws + 16777216);
  bf16_t* wkt = wqt + 1048576;
  bf16_t* wvt = wkt + 1048576;
  bf16_t* Qb = (bf16_t*)(ws + 16777216 + 6291456);
  bf16_t* Kb = Qb + 8388608;
  bf16_t* VT = Kb + 8388608;

  // 1. conversions
  convert_x_kernel<<<8192, 256, 0, stream>>>(x, xb);
  convert_transpose_w_kernel<<<dim3(1024, 1, 3), 256, 0, stream>>>(Wq, Wk, Wv, wqt);

  // 2. projections: [8192,1024] = [8192,1024] x [1024,1024]^T
  dim3 gp(8, 64, 1);
  gemm_bt_kernel<0, false, false><<<gp, 256, 0, stream>>>(
      xb, wqt, Qb, 8192, 1024, 1024, 1024, 1024, 1024);
  gemm_bt_kernel<0, false, false><<<gp, 256, 0, stream>>>(
      xb, wkt, Kb, 8192, 1024, 1024, 1024, 1024, 1024);
  gemm_bt_kernel<1, false, false><<<gp, 256, 0, stream>>>(
      xb, wvt, VT, 8192, 1024, 1024, 1024, 1024, 1024);

  // 3. per-batch attention: S = Q K^T (causal skip), softmax->P (in place,
  //    bf16, row pitch 4096 elems), O = P V  (k-loop causal-limited)
  for (int b = 0; b < 4; ++b) {
    const size_t qoff = (size_t)b * 2048 * 1024;
    gemm_bt_kernel<2, true, false><<<dim3(16, 16, 1), 256, 0, stream>>>(
        Qb + qoff, Kb + qoff, S, 2048, 2048, 1024, 1024, 1024, 2048);
    softmax_causal_kernel<<<512, 256, 0, stream>>>(S);
    gemm_bt_kernel<2, false, true><<<dim3(8, 16, 1), 256, 0, stream>>>(
        (const bf16_t*)S, VT + qoff, out + qoff, 2048, 1024, 2048, 4096, 2048, 1024);
  }
}

// Round 2
// 208.812 us; speedup vs baseline: 2.0114x; 2.0114x over previous
//
#include <hip/hip_runtime.h>
#include <hip/hip_bf16.h>
#include <stdint.h>

using bf16_t = __hip_bfloat16;
typedef __bf16 bf16x8 __attribute__((ext_vector_type(8)));
typedef float f32x4 __attribute__((ext_vector_type(4)));

// ---------------------------------------------------------------- helpers
__device__ __forceinline__ void async_lds16(const void* g, void* l) {
  // global -> LDS direct copy, 16B per lane. LDS dest is wave-uniform base +
  // lane*16 (guide m104/m108); we pass the wave-uniform base pointer.
  __builtin_amdgcn_global_load_lds(
      (const __attribute__((address_space(1))) void*)g,
      (__attribute__((address_space(3))) void*)l, 16, 0, 0);
}

__device__ __forceinline__ unsigned short f2bf_u16(float f) {
  __hip_bfloat16 h = __float2bfloat16(f);
  return __builtin_bit_cast(unsigned short, h);
}

// ---------------------------------------------------------------- convert x
__global__ __launch_bounds__(256) void convert_x_kernel(
    const float* __restrict__ x, bf16_t* __restrict__ xb) {
  size_t i = ((size_t)blockIdx.x * 256 + threadIdx.x) * 4;
  float4 v = *(const float4*)(x + i);
  ushort4 o;
  o.x = f2bf_u16(v.x);
  o.y = f2bf_u16(v.y);
  o.z = f2bf_u16(v.z);
  o.w = f2bf_u16(v.w);
  *(ushort4*)(xb + i) = o;
}

// ------------------------------------------------ convert + transpose W (3x)
// W: [1024][1024] f32 row-major  ->  WT: [1024][1024] bf16, WT[n][k]=W[k][n]
// The three WT blocks are contiguous -> one stacked [3072][1024] B^T operand.
__global__ __launch_bounds__(256) void convert_transpose_w_kernel(
    const float* __restrict__ Wq, const float* __restrict__ Wk,
    const float* __restrict__ Wv, bf16_t* __restrict__ wt) {
  __shared__ bf16_t tile[32][33];
  const float* W = (blockIdx.z == 0) ? Wq : (blockIdx.z == 1) ? Wk : Wv;
  bf16_t* WT = wt + (size_t)blockIdx.z * 1024 * 1024;
  const int tx = threadIdx.x & 31;
  const int ty = threadIdx.x >> 5;           // 0..7
  const int bx = blockIdx.x & 31;            // col tile
  const int by = blockIdx.x >> 5;            // row tile
  const int k0 = by * 32, n0 = bx * 32;
#pragma unroll
  for (int j = 0; j < 32; j += 8)
    tile[ty + j][tx] = __float2bfloat16(W[(size_t)(k0 + ty + j) * 1024 + n0 + tx]);
  __syncthreads();
#pragma unroll
  for (int j = 0; j < 32; j += 8)
    WT[(size_t)(n0 + ty + j) * 1024 + k0 + tx] = tile[tx][ty + j];
}

// ---------------------------------------------------------------- GEMM
// C[M,N] = A[M,K] * BT[N,K]^T   (both operands k-contiguous bf16)
// 128x128 tile, BK=32, 256 threads = 4 waves (2x2), 64x64 per wave,
// mfma_f32_16x16x32_bf16, global_load_lds width-16 staging (m97 structure).
// blockIdx.z selects batch: A/BT/C advance by aBatch/bBatch/cBatch elements.
// OUT_MODE: 2 = f32 row-major (Cv)
//           3 = QKV routing: n0<1024 -> Cv (bf16 row-major, 1024 pitch)
//                            n0<2048 -> Cv2 (bf16 row-major, 1024 pitch)
//                            else    -> Cv3 (bf16 V^T batched [4][1024][2048])
template <int OUT_MODE, bool CAUSAL_SKIP, bool KLIMIT>
__global__ __launch_bounds__(256) void gemm_bt_kernel(
    const bf16_t* __restrict__ A, const bf16_t* __restrict__ BT,
    void* __restrict__ Cv, void* __restrict__ Cv2, void* __restrict__ Cv3,
    int M, int N, int K, int lda, int ldb, int ldc,
    long long aBatch, long long bBatch, long long cBatch) {
  const int m0 = blockIdx.y * 128;
  const int n0 = blockIdx.x * 128;
  if (CAUSAL_SKIP && n0 > m0) return;  // tile entirely above causal diagonal
  A += (size_t)blockIdx.z * aBatch;
  BT += (size_t)blockIdx.z * bBatch;
  int nkt = K >> 5;
  if (KLIMIT) {
    int lim = (m0 + 128) >> 5;  // causal: only k (= s) < tile row max needed
    nkt = nkt < lim ? nkt : lim;
  }

  __shared__ bf16_t lsA[128 * 32];
  __shared__ bf16_t lsB[128 * 32];

  const int tid = threadIdx.x;
  const int wid = tid >> 6;
  const int lane = tid & 63;
  const int wr = wid >> 1;  // wave row 0..1
  const int wc = wid & 1;   // wave col 0..1

  f32x4 acc[4][4];
  const f32x4 zero = {0.f, 0.f, 0.f, 0.f};
#pragma unroll
  for (int m = 0; m < 4; ++m)
#pragma unroll
    for (int n = 0; n < 4; ++n) acc[m][n] = zero;

  // staging addressing: thread tid covers LDS bytes tid*16 (+4096 for 2nd half)
  const int srow = tid >> 2;       // 0..63 row within half tile
  const int scol = (tid & 3) * 8;  // k-col base
  const bf16_t* gA = A + (size_t)(m0 + srow) * lda + scol;
  const bf16_t* gB = BT + (size_t)(n0 + srow) * ldb + scol;
  const size_t gAstep64 = (size_t)64 * lda;
  const size_t gBstep64 = (size_t)64 * ldb;

  bf16_t* lA0 = lsA + wid * 512;
  bf16_t* lA1 = lsA + 2048 + wid * 512;
  bf16_t* lB0 = lsB + wid * 512;
  bf16_t* lB1 = lsB + 2048 + wid * 512;

  // fragment addressing (A: row=lane&15, k=(lane>>4)*8; B^T rows likewise)
  const int frow = lane & 15;
  const int fk = (lane >> 4) * 8;
  const int aoff = (wr * 64 + frow) * 32 + fk;
  const int boff = (wc * 64 + frow) * 32 + fk;

  for (int kt = 0; kt < nkt; ++kt) {
    __syncthreads();  // previous tile's ds_reads are done (lgkm drained)
    async_lds16(gA, lA0);
    async_lds16(gA + gAstep64, lA1);
    async_lds16(gB, lB0);
    async_lds16(gB + gBstep64, lB1);
    gA += 32;
    gB += 32;
    __syncthreads();  // compiler inserts vmcnt(0) drain before barrier

    bf16x8 af[4], bfr[4];
#pragma unroll
    for (int m = 0; m < 4; ++m)
      af[m] = *(const bf16x8*)(lsA + aoff + m * 16 * 32);
#pragma unroll
    for (int n = 0; n < 4; ++n)
      bfr[n] = *(const bf16x8*)(lsB + boff + n * 16 * 32);
#pragma unroll
    for (int m = 0; m < 4; ++m)
#pragma unroll
      for (int n = 0; n < 4; ++n)
        acc[m][n] =
            __builtin_amdgcn_mfma_f32_16x16x32_bf16(af[m], bfr[n], acc[m][n], 0, 0, 0);
  }

  // epilogue: C/D frag layout col=lane&15, row=(lane>>4)*4+j (m89/m91)
  const int erow = wr * 64 + (lane >> 4) * 4;
  const int ecol = wc * 64 + (lane & 15);
  if (OUT_MODE == 2) {
    float* C = (float*)Cv + (size_t)blockIdx.z * cBatch;
#pragma unroll
    for (int m = 0; m < 4; ++m)
#pragma unroll
      for (int n = 0; n < 4; ++n)
#pragma unroll
        for (int j = 0; j < 4; ++j) {
          int r = m0 + erow + m * 16 + j;
          int c = n0 + ecol + n * 16;
          C[(size_t)r * ldc + c] = acc[m][n][j];
        }
  } else {  // OUT_MODE == 3: QKV routing
    if (n0 < 2048) {
      bf16_t* C = (bf16_t*)((n0 < 1024) ? Cv : Cv2);
      const int cbase = (n0 < 1024) ? 0 : 1024;
#pragma unroll
      for (int m = 0; m < 4; ++m)
#pragma unroll
        for (int n = 0; n < 4; ++n)
#pragma unroll
          for (int j = 0; j < 4; ++j) {
            int r = m0 + erow + m * 16 + j;
            int c = n0 + ecol + n * 16 - cbase;
            C[(size_t)r * 1024 + c] = __float2bfloat16(acc[m][n][j]);
          }
    } else {
      // V^T batched: row r in [0,8192) -> b=r>>11, t=r&2047
      // VT[b][d][t] at ((b*1024 + d)*2048 + t)
      bf16_t* C = (bf16_t*)Cv3;
#pragma unroll
      for (int m = 0; m < 4; ++m)
#pragma unroll
        for (int n = 0; n < 4; ++n)
#pragma unroll
          for (int j = 0; j < 4; ++j) {
            int r = m0 + erow + m * 16 + j;
            int c = n0 + ecol + n * 16 - 2048;
            int b = r >> 11, t = r & 2047;
            C[((size_t)b * 1024 + c) * 2048 + t] = __float2bfloat16(acc[m][n][j]);
          }
    }
  }
}

// ---------------------------------------------------------------- softmax
// One wave per (b,t) row: read S[b][t][0..2047] f32, causal-masked softmax of
// scale*S, write P bf16 IN PLACE at the row start (row is fully
// register-staged before any store). Upper triangle written as 0.
// Row pitch stays 2048 f32 = 4096 bf16 elements.
__global__ __launch_bounds__(256) void softmax_causal_kernel(float* __restrict__ S) {
  const int lane = threadIdx.x & 63;
  const int rg = blockIdx.x * 4 + (threadIdx.x >> 6);
  const int b = rg >> 11;        // batch (0 for per-batch fallback grids)
  const int t = rg & 2047;       // row within batch = causal limit
  float* srow = S + (size_t)b * 2048 * 2048 + (size_t)t * 2048;

  float4 v[8];
#pragma unroll
  for (int it = 0; it < 8; ++it) v[it] = *(const float4*)(srow + (it * 64 + lane) * 4);

  float mx = -3.0e38f;
#pragma unroll
  for (int it = 0; it < 8; ++it) {
    int s0 = (it * 64 + lane) * 4;
    if (s0 + 0 <= t) mx = fmaxf(mx, v[it].x);
    if (s0 + 1 <= t) mx = fmaxf(mx, v[it].y);
    if (s0 + 2 <= t) mx = fmaxf(mx, v[it].z);
    if (s0 + 3 <= t) mx = fmaxf(mx, v[it].w);
  }
#pragma unroll
  for (int off = 32; off > 0; off >>= 1) mx = fmaxf(mx, __shfl_xor(mx, off, 64));

  const float kMul = 0.03125f * 1.4426950408889634f;  // scale * log2(e)
  float p[8][4];
  float sum = 0.f;
#pragma unroll
  for (int it = 0; it < 8; ++it) {
    int s0 = (it * 64 + lane) * 4;
    float e0 = (s0 + 0 <= t) ? exp2f((v[it].x - mx) * kMul) : 0.f;
    float e1 = (s0 + 1 <= t) ? exp2f((v[it].y - mx) * kMul) : 0.f;
    float e2 = (s0 + 2 <= t) ? exp2f((v[it].z - mx) * kMul) : 0.f;
    float e3 = (s0 + 3 <= t) ? exp2f((v[it].w - mx) * kMul) : 0.f;
    p[it][0] = e0; p[it][1] = e1; p[it][2] = e2; p[it][3] = e3;
    sum += (e0 + e1) + (e2 + e3);
  }
#pragma unroll
  for (int off = 32; off > 0; off >>= 1) sum += __shfl_xor(sum, off, 64);
  const float inv = 1.f / sum;

  bf16_t* prow = (bf16_t*)srow;  // in-place: bf16 row occupies first 4KB of row
#pragma unroll
  for (int it = 0; it < 8; ++it) {
    ushort4 o;
    o.x = f2bf_u16(p[it][0] * inv);
    o.y = f2bf_u16(p[it][1] * inv);
    o.z = f2bf_u16(p[it][2] * inv);
    o.w = f2bf_u16(p[it][3] * inv);
    *(ushort4*)(prow + (it * 64 + lane) * 4) = o;
  }
}

// ---------------------------------------------------------------- launch
extern "C" void kernel_launch(void* const* d_in, const int* in_sizes, int n_in,
                              void* d_out, int out_size, void* d_ws, size_t ws_size,
                              hipStream_t stream) {
  (void)in_sizes; (void)n_in; (void)out_size;
  const float* x = (const float*)d_in[0];
  const float* Wq = (const float*)d_in[1];
  const float* Wk = (const float*)d_in[2];
  const float* Wv = (const float*)d_in[3];
  float* out = (float*)d_out;

  char* ws = (char*)d_ws;
  // batched layout (requires ~118 MiB):
  //   [0, 67.1M)        S_all (f32 [4][2048][2048]); xb (bf16 8192x1024,
  //                     16.8M) aliases the front -- dead before S written
  //   [67.1M, 73.4M)    WT (bf16 [3072][1024], Wq^T|Wk^T|Wv^T stacked)
  //   [73.4M, 90.2M)    Q  (bf16 8192x1024)
  //   [90.2M, 107.0M)   K  (bf16 8192x1024)
  //   [107.0M, 123.7M)  VT (bf16 [4][1024][2048])
  const size_t NEED = 123731968;
  const bool batched = ws_size >= NEED;

  bf16_t* xb = (bf16_t*)ws;
  float* S;
  bf16_t *WT, *Qb, *Kb, *VT;
  if (batched) {
    S = (float*)ws;
    WT = (bf16_t*)(ws + 67108864);
    Qb = (bf16_t*)(ws + 73400320);
    Kb = (bf16_t*)(ws + 90177536);
    VT = (bf16_t*)(ws + 106954752);
  } else {  // round-1 layout: per-batch S aliases xb
    S = (float*)ws;
    WT = (bf16_t*)(ws + 16777216);
    Qb = (bf16_t*)(ws + 16777216 + 6291456);
    Kb = Qb + 8388608;
    VT = Kb + 8388608;
  }

  // 1. conversions
  convert_x_kernel<<<8192, 256, 0, stream>>>(x, xb);
  convert_transpose_w_kernel<<<dim3(1024, 1, 3), 256, 0, stream>>>(Wq, Wk, Wv, WT);

  // 2. merged QKV projection: [8192,3072] = [8192,1024] x [3072,1024]^T
  //    routing epilogue -> Q, K row-major; V transposed batched.
  gemm_bt_kernel<3, false, false><<<dim3(24, 64, 1), 256, 0, stream>>>(
      xb, WT, Qb, Kb, VT, 8192, 3072, 1024, 1024, 1024, 0, 0, 0, 0);

  if (batched) {
    // 3. S = Q K^T for all batches (causal tile skip)
    gemm_bt_kernel<2, true, false><<<dim3(16, 16, 4), 256, 0, stream>>>(
        Qb, Kb, S, nullptr, nullptr, 2048, 2048, 1024, 1024, 1024, 2048,
        2097152LL, 2097152LL, 4194304LL);
    // 4. softmax -> P (bf16 in place, row pitch 4096 elems)
    softmax_causal_kernel<<<2048, 256, 0, stream>>>(S);
    // 5. O = P V for all batches (k-loop causal-limited)
    gemm_bt_kernel<2, false, true><<<dim3(8, 16, 4), 256, 0, stream>>>(
        (const bf16_t*)S, VT, out, nullptr, nullptr, 2048, 1024, 2048, 4096,
        2048, 1024, 8388608LL, 2097152LL, 2097152LL);
  } else {
    for (int b = 0; b < 4; ++b) {
      const size_t qoff = (size_t)b * 2048 * 1024;
      gemm_bt_kernel<2, true, false><<<dim3(16, 16, 1), 256, 0, stream>>>(
          Qb + qoff, Kb + qoff, S, nullptr, nullptr, 2048, 2048, 1024, 1024,
          1024, 2048, 0, 0, 0);
      softmax_causal_kernel<<<512, 256, 0, stream>>>(S);
      gemm_bt_kernel<2, false, true><<<dim3(8, 16, 1), 256, 0, stream>>>(
          (const bf16_t*)S, VT + qoff, out + qoff, nullptr, nullptr, 2048,
          1024, 2048, 4096, 2048, 1024, 0, 0, 0);
    }
  }
}

// Round 3
// 186.968 us; speedup vs baseline: 2.2464x; 1.1168x over previous
//
#include <hip/hip_runtime.h>
#include <hip/hip_bf16.h>
#include <stdint.h>

using bf16_t = __hip_bfloat16;
typedef __bf16 bf16x8 __attribute__((ext_vector_type(8)));
typedef float f32x4 __attribute__((ext_vector_type(4)));

// ---------------------------------------------------------------- helpers
__device__ __forceinline__ void async_lds16(const void* g, void* l) {
  // global -> LDS direct copy, 16B/lane. LDS dest = wave-uniform base +
  // lane*16 (m104/m108); global source is per-lane (m173).
  __builtin_amdgcn_global_load_lds(
      (const __attribute__((address_space(1))) void*)g,
      (__attribute__((address_space(3))) void*)l, 16, 0, 0);
}

__device__ __forceinline__ unsigned short f2bf_u16(float f) {
  __hip_bfloat16 h = __float2bfloat16(f);
  return __builtin_bit_cast(unsigned short, h);
}

// ---------------------------------------------------------------- convert x
__global__ __launch_bounds__(256) void convert_x_kernel(
    const float* __restrict__ x, bf16_t* __restrict__ xb) {
  size_t i = ((size_t)blockIdx.x * 256 + threadIdx.x) * 4;
  float4 v = *(const float4*)(x + i);
  ushort4 o;
  o.x = f2bf_u16(v.x);
  o.y = f2bf_u16(v.y);
  o.z = f2bf_u16(v.z);
  o.w = f2bf_u16(v.w);
  *(ushort4*)(xb + i) = o;
}

// ------------------------------------------------ convert + transpose W (3x)
__global__ __launch_bounds__(256) void convert_transpose_w_kernel(
    const float* __restrict__ Wq, const float* __restrict__ Wk,
    const float* __restrict__ Wv, bf16_t* __restrict__ wt) {
  __shared__ bf16_t tile[32][33];
  const float* W = (blockIdx.z == 0) ? Wq : (blockIdx.z == 1) ? Wk : Wv;
  bf16_t* WT = wt + (size_t)blockIdx.z * 1024 * 1024;
  const int tx = threadIdx.x & 31;
  const int ty = threadIdx.x >> 5;
  const int bx = blockIdx.x & 31;
  const int by = blockIdx.x >> 5;
  const int k0 = by * 32, n0 = bx * 32;
#pragma unroll
  for (int j = 0; j < 32; j += 8)
    tile[ty + j][tx] = __float2bfloat16(W[(size_t)(k0 + ty + j) * 1024 + n0 + tx]);
  __syncthreads();
#pragma unroll
  for (int j = 0; j < 32; j += 8)
    WT[(size_t)(n0 + ty + j) * 1024 + k0 + tx] = tile[tx][ty + j];
}

// ---------------------------------------------------------------- GEMM
// C[M,N] = A[M,K] * BT[N,K]^T, both operands k-contiguous bf16.
// 128(M) x 256(N) tile, BK=32, 512 threads = 8 waves (2M x 4N), 64x64/wave.
// 3 LDS buffers, counted-vmcnt pipeline (T3/T4): stage tile t+2 while
// computing tile t; boundary s_waitcnt vmcnt(3) guarantees tile t+1 landed.
// T2 swizzle: 16B slot s' = s ^ ((row>>1)&3), applied on the GLOBAL source
// (LDS written linearly by global_load_lds) and on the ds_read address.
// OUT_MODE: 2 = f32 row-major; 3 = QKV routing (Q,K bf16 row-major; V^T).
template <int OUT_MODE, bool CAUSAL_SKIP, bool KLIMIT, bool XCDSWZ>
__global__ __launch_bounds__(512, 2) void gemm_pipe_kernel(
    const bf16_t* __restrict__ A, const bf16_t* __restrict__ BT,
    void* __restrict__ Cv, void* __restrict__ Cv2, void* __restrict__ Cv3,
    int M, int N, int K, int lda, int ldb, int ldc,
    long long aBatch, long long bBatch, long long cBatch) {
  int bx = blockIdx.x, by = blockIdx.y;
  if (XCDSWZ) {
    // bijective XCD swizzle (grid size must be a multiple of 8)
    const int gx = gridDim.x;
    const int nwg = gx * gridDim.y;
    const int id = by * gx + bx;
    const int cpx = nwg >> 3;
    const int swz = (id & 7) * cpx + (id >> 3);
    by = swz / gx;
    bx = swz % gx;
  }
  const int m0 = by * 128;
  const int n0 = bx * 256;
  if (CAUSAL_SKIP && 2 * bx > by) return;  // tile fully above causal diagonal
  A += (size_t)blockIdx.z * aBatch;
  BT += (size_t)blockIdx.z * bBatch;
  int nkt = K >> 5;
  if (KLIMIT) {
    int lim = (m0 + 128) >> 5;
    nkt = nkt < lim ? nkt : lim;
  }

  __shared__ bf16_t lsA[3 * 128 * 32];  // 24 KB, buffer stride 4096 elems
  __shared__ bf16_t lsB[3 * 256 * 32];  // 48 KB, buffer stride 8192 elems

  const int tid = threadIdx.x;
  const int wid = tid >> 6;
  const int lane = tid & 63;
  const int wm = wid >> 2;  // 0..1
  const int wn = wid & 3;   // 0..3

  // ---- stage source addressing (pre-swizzled global column)
  const int sr = tid >> 2;                  // row 0..127 within (half-)tile
  const int ss = tid & 3;                   // 16B slot 0..3
  const int sswz = ss ^ ((sr >> 1) & 3);    // T2 involution
  const bf16_t* gA = A + (size_t)(m0 + sr) * lda + sswz * 8;
  const bf16_t* gB0 = BT + (size_t)(n0 + sr) * ldb + sswz * 8;
  const bf16_t* gB1 = BT + (size_t)(n0 + 128 + sr) * ldb + sswz * 8;

  // ---- fragment read addressing (swizzled ds_read)
  const int kslot = (lane >> 4) ^ ((lane >> 1) & 3);
  const int abase = (wm * 64 + (lane & 15)) * 32 + kslot * 8;
  const int bbase = (wn * 64 + (lane & 15)) * 32 + kslot * 8;

  f32x4 acc[4][4];
  const f32x4 zero = {0.f, 0.f, 0.f, 0.f};
#pragma unroll
  for (int m = 0; m < 4; ++m)
#pragma unroll
    for (int n = 0; n < 4; ++n) acc[m][n] = zero;

  // ---- prologue: stage tiles 0 and 1; guarantee tile 0 resident
  async_lds16(gA, lsA + wid * 512);
  async_lds16(gB0, lsB + wid * 512);
  async_lds16(gB1, lsB + 4096 + wid * 512);
  if (nkt > 1) {
    async_lds16(gA + 32, lsA + 4096 + wid * 512);
    async_lds16(gB0 + 32, lsB + 8192 + wid * 512);
    async_lds16(gB1 + 32, lsB + 8192 + 4096 + wid * 512);
    asm volatile("s_waitcnt vmcnt(3)" ::: "memory");
  } else {
    asm volatile("s_waitcnt vmcnt(0)" ::: "memory");
  }
  __builtin_amdgcn_s_barrier();

  int cb = 0;  // current buffer index; stage target = (cb+2)%3
  for (int t = 0; t < nkt; ++t) {
    const bf16_t* bufA = lsA + cb * 4096;
    const bf16_t* bufB = lsB + cb * 8192;
    int sb = cb + 2;
    if (sb >= 3) sb -= 3;

    // ---------- phase 1: A frags + B frags 0,1 ; stage 2 calls ; 8 MFMA
    bf16x8 af[4], bfr[4];
#pragma unroll
    for (int mf = 0; mf < 4; ++mf)
      af[mf] = *(const bf16x8*)(bufA + abase + mf * 512);
    bfr[0] = *(const bf16x8*)(bufB + bbase);
    bfr[1] = *(const bf16x8*)(bufB + bbase + 512);
    if (t + 2 < nkt) {
      async_lds16(gA + (t + 2) * 32, lsA + sb * 4096 + wid * 512);
      async_lds16(gB0 + (t + 2) * 32, lsB + sb * 8192 + wid * 512);
    }
    __builtin_amdgcn_s_barrier();
    __builtin_amdgcn_s_setprio(1);
#pragma unroll
    for (int mf = 0; mf < 4; ++mf)
#pragma unroll
      for (int nf = 0; nf < 2; ++nf)
        acc[mf][nf] = __builtin_amdgcn_mfma_f32_16x16x32_bf16(
            af[mf], bfr[nf], acc[mf][nf], 0, 0, 0);
    __builtin_amdgcn_s_setprio(0);
    __builtin_amdgcn_s_barrier();

    // ---------- phase 2: B frags 2,3 ; stage 1 call ; vmcnt ; 8 MFMA
    bfr[2] = *(const bf16x8*)(bufB + bbase + 1024);
    bfr[3] = *(const bf16x8*)(bufB + bbase + 1536);
    if (t + 2 < nkt)
      async_lds16(gB1 + (t + 2) * 32, lsB + sb * 8192 + 4096 + wid * 512);
    if (t + 2 < nkt) {
      asm volatile("s_waitcnt vmcnt(3)" ::: "memory");  // tile t+1 resident
    } else if (t + 2 == nkt) {
      asm volatile("s_waitcnt vmcnt(0)" ::: "memory");  // drain last prefetch
    }
    __builtin_amdgcn_s_barrier();
    __builtin_amdgcn_s_setprio(1);
#pragma unroll
    for (int mf = 0; mf < 4; ++mf)
#pragma unroll
      for (int nf = 2; nf < 4; ++nf)
        acc[mf][nf] = __builtin_amdgcn_mfma_f32_16x16x32_bf16(
            af[mf], bfr[nf], acc[mf][nf], 0, 0, 0);
    __builtin_amdgcn_s_setprio(0);
    __builtin_amdgcn_s_barrier();

    cb = cb + 1;
    if (cb >= 3) cb -= 3;
  }

  // ---- epilogue: C/D frag layout col=lane&15, row=(lane>>4)*4+j (m89/m91)
  const int erow = wm * 64 + (lane >> 4) * 4;
  const int ecol = wn * 64 + (lane & 15);
  if (OUT_MODE == 2) {
    float* C = (float*)Cv + (size_t)blockIdx.z * cBatch;
#pragma unroll
    for (int m = 0; m < 4; ++m)
#pragma unroll
      for (int n = 0; n < 4; ++n)
#pragma unroll
        for (int j = 0; j < 4; ++j) {
          int r = m0 + erow + m * 16 + j;
          int c = n0 + ecol + n * 16;
          C[(size_t)r * ldc + c] = acc[m][n][j];
        }
  } else {  // OUT_MODE == 3: QKV routing (n0 is 256-aligned, regions 1024-wide)
    if (n0 < 2048) {
      bf16_t* C = (bf16_t*)((n0 < 1024) ? Cv : Cv2);
      const int cb0 = n0 & 1023;
#pragma unroll
      for (int m = 0; m < 4; ++m)
#pragma unroll
        for (int n = 0; n < 4; ++n)
#pragma unroll
          for (int j = 0; j < 4; ++j) {
            int r = m0 + erow + m * 16 + j;
            int c = cb0 + ecol + n * 16;
            C[(size_t)r * 1024 + c] = __float2bfloat16(acc[m][n][j]);
          }
    } else {
      // V^T batched: row r in [0,8192) -> b=r>>11, t=r&2047 ; VT[b][d][t]
      bf16_t* C = (bf16_t*)Cv3;
      const int d0 = n0 - 2048;
#pragma unroll
      for (int m = 0; m < 4; ++m)
#pragma unroll
        for (int n = 0; n < 4; ++n)
#pragma unroll
          for (int j = 0; j < 4; ++j) {
            int r = m0 + erow + m * 16 + j;
            int d = d0 + ecol + n * 16;
            int b = r >> 11, tt = r & 2047;
            C[((size_t)b * 1024 + d) * 2048 + tt] = __float2bfloat16(acc[m][n][j]);
          }
    }
  }
}

// ---------------------------------------------------------------- softmax
// One wave per (b,t) row; causal softmax of scale*S; P written bf16 in place
// (row fully register-staged first). Row pitch 2048 f32 = 4096 bf16.
__global__ __launch_bounds__(256) void softmax_causal_kernel(float* __restrict__ S) {
  const int lane = threadIdx.x & 63;
  const int rg = blockIdx.x * 4 + (threadIdx.x >> 6);
  const int b = rg >> 11;
  const int t = rg & 2047;
  float* srow = S + (size_t)b * 2048 * 2048 + (size_t)t * 2048;

  float4 v[8];
#pragma unroll
  for (int it = 0; it < 8; ++it) v[it] = *(const float4*)(srow + (it * 64 + lane) * 4);

  float mx = -3.0e38f;
#pragma unroll
  for (int it = 0; it < 8; ++it) {
    int s0 = (it * 64 + lane) * 4;
    if (s0 + 0 <= t) mx = fmaxf(mx, v[it].x);
    if (s0 + 1 <= t) mx = fmaxf(mx, v[it].y);
    if (s0 + 2 <= t) mx = fmaxf(mx, v[it].z);
    if (s0 + 3 <= t) mx = fmaxf(mx, v[it].w);
  }
#pragma unroll
  for (int off = 32; off > 0; off >>= 1) mx = fmaxf(mx, __shfl_xor(mx, off, 64));

  const float kMul = 0.03125f * 1.4426950408889634f;  // scale * log2(e)
  float p[8][4];
  float sum = 0.f;
#pragma unroll
  for (int it = 0; it < 8; ++it) {
    int s0 = (it * 64 + lane) * 4;
    float e0 = (s0 + 0 <= t) ? exp2f((v[it].x - mx) * kMul) : 0.f;
    float e1 = (s0 + 1 <= t) ? exp2f((v[it].y - mx) * kMul) : 0.f;
    float e2 = (s0 + 2 <= t) ? exp2f((v[it].z - mx) * kMul) : 0.f;
    float e3 = (s0 + 3 <= t) ? exp2f((v[it].w - mx) * kMul) : 0.f;
    p[it][0] = e0; p[it][1] = e1; p[it][2] = e2; p[it][3] = e3;
    sum += (e0 + e1) + (e2 + e3);
  }
#pragma unroll
  for (int off = 32; off > 0; off >>= 1) sum += __shfl_xor(sum, off, 64);
  const float inv = 1.f / sum;

  bf16_t* prow = (bf16_t*)srow;
#pragma unroll
  for (int it = 0; it < 8; ++it) {
    ushort4 o;
    o.x = f2bf_u16(p[it][0] * inv);
    o.y = f2bf_u16(p[it][1] * inv);
    o.z = f2bf_u16(p[it][2] * inv);
    o.w = f2bf_u16(p[it][3] * inv);
    *(ushort4*)(prow + (it * 64 + lane) * 4) = o;
  }
}

// ---------------------------------------------------------------- launch
extern "C" void kernel_launch(void* const* d_in, const int* in_sizes, int n_in,
                              void* d_out, int out_size, void* d_ws, size_t ws_size,
                              hipStream_t stream) {
  (void)in_sizes; (void)n_in; (void)out_size;
  const float* x = (const float*)d_in[0];
  const float* Wq = (const float*)d_in[1];
  const float* Wk = (const float*)d_in[2];
  const float* Wv = (const float*)d_in[3];
  float* out = (float*)d_out;

  char* ws = (char*)d_ws;
  // batched layout (requires ~118 MiB):
  //   [0, 67.1M)        S_all (f32 [4][2048][2048]); xb (bf16 8192x1024)
  //                     aliases the front -- dead before S written
  //   [67.1M, 73.4M)    WT (bf16 [3072][1024], Wq^T|Wk^T|Wv^T stacked)
  //   [73.4M, 90.2M)    Q  (bf16 8192x1024)
  //   [90.2M, 107.0M)   K  (bf16 8192x1024)
  //   [107.0M, 123.7M)  VT (bf16 [4][1024][2048])
  const size_t NEED = 123731968;
  const bool batched = ws_size >= NEED;

  bf16_t* xb = (bf16_t*)ws;
  float* S;
  bf16_t *WT, *Qb, *Kb, *VT;
  if (batched) {
    S = (float*)ws;
    WT = (bf16_t*)(ws + 67108864);
    Qb = (bf16_t*)(ws + 73400320);
    Kb = (bf16_t*)(ws + 90177536);
    VT = (bf16_t*)(ws + 106954752);
  } else {
    S = (float*)ws;
    WT = (bf16_t*)(ws + 16777216);
    Qb = (bf16_t*)(ws + 16777216 + 6291456);
    Kb = Qb + 8388608;
    VT = Kb + 8388608;
  }

  // 1. conversions
  convert_x_kernel<<<8192, 256, 0, stream>>>(x, xb);
  convert_transpose_w_kernel<<<dim3(1024, 1, 3), 256, 0, stream>>>(Wq, Wk, Wv, WT);

  // 2. merged QKV projection: [8192,3072] = [8192,1024] x [3072,1024]^T
  //    (768 blocks, XCD-swizzled: 768 % 8 == 0)
  gemm_pipe_kernel<3, false, false, true><<<dim3(12, 64, 1), 512, 0, stream>>>(
      xb, WT, Qb, Kb, VT, 8192, 3072, 1024, 1024, 1024, 0, 0, 0, 0);

  if (batched) {
    // 3. S = Q K^T, all batches (causal tile skip)
    gemm_pipe_kernel<2, true, false, false><<<dim3(8, 16, 4), 512, 0, stream>>>(
        Qb, Kb, S, nullptr, nullptr, 2048, 2048, 1024, 1024, 1024, 2048,
        2097152LL, 2097152LL, 4194304LL);
    // 4. softmax -> P (bf16 in place, row pitch 4096 elems)
    softmax_causal_kernel<<<2048, 256, 0, stream>>>(S);
    // 5. O = P V, all batches (k-loop causal-limited)
    gemm_pipe_kernel<2, false, true, false><<<dim3(4, 16, 4), 512, 0, stream>>>(
        (const bf16_t*)S, VT, out, nullptr, nullptr, 2048, 1024, 2048, 4096,
        2048, 1024, 8388608LL, 2097152LL, 2097152LL);
  } else {
    for (int b = 0; b < 4; ++b) {
      const size_t qoff = (size_t)b * 2048 * 1024;
      gemm_pipe_kernel<2, true, false, false><<<dim3(8, 16, 1), 512, 0, stream>>>(
          Qb + qoff, Kb + qoff, S, nullptr, nullptr, 2048, 2048, 1024, 1024,
          1024, 2048, 0, 0, 0);
      softmax_causal_kernel<<<512, 256, 0, stream>>>(S);
      gemm_pipe_kernel<2, false, true, false><<<dim3(4, 16, 1), 512, 0, stream>>>(
          (const bf16_t*)S, VT + qoff, out + qoff, nullptr, nullptr, 2048,
          1024, 2048, 4096, 2048, 1024, 0, 0, 0);
    }
  }
}